// Round 11
// baseline (180.124 us; speedup 1.0000x reference)
//
#include <hip/hip_runtime.h>

// Problem constants
#define BB  16
#define JJ  32
#define HH  512
#define WW  512
#define KK  9
#define PAD 3
#define OH  510
#define OW  510

// No-im2col implicit GEMM (round-10 structure + XCD swizzle). ONE change:
// 2-row D-buffer ping -- compute rows r,r+1 back-to-back, then store both,
// plane-major, so each output plane receives a 2x512B burst within one
// ~2KB DRAM page span per phase (doubles per-page delivery; attacks the
// measured ~50% DRAM write efficiency = 3.0 vs 6.3 TB/s). Also halves
// barrier count. LDS 35840->52224 B => 3 blocks/CU (store-bound, ok).
#define NPIX   128
#define RROWS  8
#define NRAW   16
#define NCHUNK 18
#define CPY_PITCH 288              // 18*16 B
#define ROW_PITCH 1184             // 4*288 + 32
#define IN_BYTES  (NRAW * ROW_PITCH)   // 18944

#define D_JP   260                 // words per j (2 rows x 130); 260%32=4
#define D_RP   130                 // words per row within j
#define DBUF_OFF  IN_BYTES
#define LDS_BYTES (DBUF_OFF + JJ * D_JP * 4)   // 18944 + 33280 = 52224

// raw f32 weight region (union with input+D regions, used before staging)
#define WJ_PITCH 656
#define W_RAW_BYTES (JJ * WJ_PITCH)   // 20992 <= LDS_BYTES

typedef __bf16 bf16x8 __attribute__((ext_vector_type(8)));
typedef float  f32x4  __attribute__((ext_vector_type(4)));

__device__ __forceinline__ unsigned pack2bf(float a, float b) {
    unsigned ua = __float_as_uint(a) + 0x8000u;
    unsigned ub = __float_as_uint(b) + 0x8000u;
    return (ua >> 16) | (ub & 0xFFFF0000u);
}

// barrier that waits only on LDS ops -- global stores stay in flight
__device__ __forceinline__ void barrier_lds_only() {
    asm volatile("s_waitcnt lgkmcnt(0)" ::: "memory");
    __builtin_amdgcn_s_barrier();
}

__global__ __launch_bounds__(256, 3)
void conv_mfma_kernel(const float* __restrict__ in,
                      const float* __restrict__ wgt,
                      float* __restrict__ out) {
    __shared__ __align__(16) char lds[LDS_BYTES];

    const int tid  = threadIdx.x;
    const int lane = tid & 63;
    const int w    = tid >> 6;
    const int col  = lane & 15;
    const int q    = lane >> 4;
    const int g    = q >> 1;
    const int h    = q & 1;

    // ---- XCD-grouping swizzle (round-10 validated) ----
    const int id  = blockIdx.x;          // flat 0..4095
    const int xcd = id & 7;
    const int xt  = (id >> 3) & 3;
    const int G   = ((id >> 5) << 3) + xcd;   // 0..1023
    const int x0  = xt * NPIX;
    const int y0  = (G & 63) * RROWS;
    const int bi  = G >> 6;

    // ---- W1: zero + fill padded raw f32 weights [32 j][10 u][16 v] ----
    {
        const uint4 z = make_uint4(0u, 0u, 0u, 0u);
        for (int idx = tid; idx < W_RAW_BYTES / 16; idx += 256)
            *(uint4*)(lds + idx * 16) = z;
    }
    __syncthreads();
    const float* wB = wgt + (size_t)bi * JJ * (KK * KK);
    for (int idx = tid; idx < JJ * KK * KK; idx += 256) {
        const int j   = idx / (KK * KK);
        const int rem = idx - j * (KK * KK);
        const int u   = rem / KK;
        const int v   = rem - u * KK;
        *(float*)(lds + j * WJ_PITCH + u * 64 + v * 4) = wB[idx];
    }
    __syncthreads();

    // ---- W2: A fragments (weights) to registers ----
    bf16x8 afrag[5][2];
    #pragma unroll
    for (int s = 0; s < 5; ++s) {
        const int u = 2 * s + g;          // 0..9 (u=9 row zeroed)
        #pragma unroll
        for (int mt = 0; mt < 2; ++mt) {
            const char* p = lds + (mt * 16 + col) * WJ_PITCH + u * 64 + h * 32;
            const float4 fa = *(const float4*)p;
            const float4 fb = *(const float4*)(p + 16);
            const uint4 pk = make_uint4(pack2bf(fa.x, fa.y), pack2bf(fa.z, fa.w),
                                        pack2bf(fb.x, fb.y), pack2bf(fb.z, fb.w));
            afrag[s][mt] = __builtin_bit_cast(bf16x8, pk);
        }
    }
    __syncthreads();   // weight region reused below

    // ---- stage raw input rows as 4 shifted bf16 copies ----
    const float* inB = in + (size_t)bi * (HH * WW);
    #pragma unroll 1
    for (int idx = tid; idx < NRAW * NCHUNK; idx += 256) {
        const int rr = idx / NCHUNK;
        const int m  = idx - rr * NCHUNK;
        const int gr = y0 - PAD + rr;
        const int gc0 = x0 - PAD + 8 * m;
        const bool rok = ((unsigned)gr < (unsigned)HH);
        float el[11];
        #pragma unroll
        for (int e = 0; e < 11; ++e) {
            const int gc = gc0 + e;
            el[e] = (rok && (unsigned)gc < (unsigned)WW) ? inB[gr * WW + gc] : 0.f;
        }
        unsigned P[5], Q[5];
        #pragma unroll
        for (int i = 0; i < 5; ++i) {
            P[i] = pack2bf(el[2 * i],     el[2 * i + 1]);
            Q[i] = pack2bf(el[2 * i + 1], el[2 * i + 2]);
        }
        char* base = lds + rr * ROW_PITCH + m * 16;
        *(uint4*)(base)                 = make_uint4(P[0], P[1], P[2], P[3]);
        *(uint4*)(base + CPY_PITCH)     = make_uint4(Q[0], Q[1], Q[2], Q[3]);
        *(uint4*)(base + 2 * CPY_PITCH) = make_uint4(P[1], P[2], P[3], P[4]);
        *(uint4*)(base + 3 * CPY_PITCH) = make_uint4(Q[1], Q[2], Q[3], Q[4]);
    }
    __syncthreads();

    // ---- main loop: 4 iterations x 2 output rows ----
    const int ec   = col & 3;                       // copy index
    const int e0   = w * 32 + col + 8 * h;          // fragment start element
    const int boff = ec * CPY_PITCH + (e0 - ec) * 2;
    float* D = (float*)(lds + DBUF_OFF);
    const size_t plane = (size_t)OH * OW;
    float* outB = out + (size_t)bi * JJ * plane;

    #pragma unroll 1
    for (int r2 = 0; r2 < RROWS / 2; ++r2) {
        // compute rows 2*r2 and 2*r2+1 back-to-back into D slots 0/1
        #pragma unroll
        for (int rr = 0; rr < 2; ++rr) {
            const int r = r2 * 2 + rr;
            f32x4 acc00 = {0.f, 0.f, 0.f, 0.f};
            f32x4 acc01 = {0.f, 0.f, 0.f, 0.f};
            f32x4 acc10 = {0.f, 0.f, 0.f, 0.f};
            f32x4 acc11 = {0.f, 0.f, 0.f, 0.f};

            #pragma unroll
            for (int s = 0; s < 5; ++s) {
                int u = 2 * s + g;
                if (u > 8) u = 0;             // afrag==0 there; any finite B ok
                const char* rowp = lds + (r + u) * ROW_PITCH + boff;
                const uint2 l0 = *(const uint2*)(rowp);
                const uint2 h0 = *(const uint2*)(rowp + 8);
                const uint2 l1 = *(const uint2*)(rowp + 32);
                const uint2 h1 = *(const uint2*)(rowp + 40);
                const bf16x8 b0 = __builtin_bit_cast(bf16x8, make_uint4(l0.x, l0.y, h0.x, h0.y));
                const bf16x8 b1 = __builtin_bit_cast(bf16x8, make_uint4(l1.x, l1.y, h1.x, h1.y));
                acc00 = __builtin_amdgcn_mfma_f32_16x16x32_bf16(afrag[s][0], b0, acc00, 0, 0, 0);
                acc01 = __builtin_amdgcn_mfma_f32_16x16x32_bf16(afrag[s][0], b1, acc01, 0, 0, 0);
                acc10 = __builtin_amdgcn_mfma_f32_16x16x32_bf16(afrag[s][1], b0, acc10, 0, 0, 0);
                acc11 = __builtin_amdgcn_mfma_f32_16x16x32_bf16(afrag[s][1], b1, acc11, 0, 0, 0);
            }

            // D write: D[j][rr][px], j = mt*16 + q*4 + rg, px = w*32+col(+16)
            const int pxb = w * 32 + col;
            #pragma unroll
            for (int rg = 0; rg < 4; ++rg) {
                D[(q * 4 + rg) * D_JP + rr * D_RP + pxb]           = acc00[rg];
                D[(q * 4 + rg) * D_JP + rr * D_RP + pxb + 16]      = acc01[rg];
                D[(16 + q * 4 + rg) * D_JP + rr * D_RP + pxb]      = acc10[rg];
                D[(16 + q * 4 + rg) * D_JP + rr * D_RP + pxb + 16] = acc11[rg];
            }
        }
        barrier_lds_only();   // D visible; global stores stay in flight

        // store: plane-major, 2 rows per plane = 2x512B in one page span
        const int px = 2 * lane;
        const int gx = x0 + px;
        if (gx + 1 < OW) {
            #pragma unroll
            for (int i = 0; i < 8; ++i) {
                const int j = w * 8 + i;
                #pragma unroll
                for (int rr = 0; rr < 2; ++rr) {
                    const int y = y0 + r2 * 2 + rr;
                    if (y < OH) {
                        const float2 v = *(const float2*)&D[j * D_JP + rr * D_RP + px];
                        *(float2*)(outB + (size_t)j * plane + (size_t)y * OW + gx) = v;
                    }
                }
            }
        }
        barrier_lds_only();   // D reads done; next iter may overwrite D
    }
}

extern "C" void kernel_launch(void* const* d_in, const int* in_sizes, int n_in,
                              void* d_out, int out_size, void* d_ws, size_t ws_size,
                              hipStream_t stream) {
    const float* inp = (const float*)d_in[0];   // [16,1,512,512] f32
    const float* wgt = (const float*)d_in[1];   // [16,32,9,9]    f32
    float* out = (float*)d_out;                 // [16,32,510,510] f32

    conv_mfma_kernel<<<dim3(4096), 256, 0, stream>>>(inp, wgt, out);
}

// Round 12
// 145.439 us; speedup vs baseline: 1.2385x; 1.2385x over previous
//
#include <hip/hip_runtime.h>

// Problem constants
#define BB  16
#define JJ  32
#define HH  512
#define WW  512
#define KK  9
#define PAD 3
#define OH  510
#define OW  510

// Full-width implicit GEMM: block = [16 j][4 rows][512 px]. Plane rows are
// contiguous in memory, so each block writes 16 runs of 4*2040 = 8160B
// CONTIGUOUS (vs 512B in r10) -- attacks the measured DRAM write-locality
// limit (3.0 vs 6.6 TB/s memset). Parity-split k-mapping (even-x subtiles
// use v-shifted weight frags) makes every B-frag start even -> 4B-aligned
// dword LDS reads -> no shifted input copies (12 rows x 1072B = 12.9 KB).
#define RROWS  4
#define NRAW   12
#define IN_DW  268                  // dwords per input row (264 used + pad)
#define IN_PITCH_B (IN_DW * 4)      // 1072
#define IN_BYTES (NRAW * IN_PITCH_B)   // 12864

#define D_PITCH 524                 // f32 per j-row (512 + pad)
#define DBUF_OFF IN_BYTES
#define LDS_BYTES (DBUF_OFF + 16 * D_PITCH * 4)   // 46400

// raw f32 weights [16 j][10 u][20 v'] (v' = v+1, zero-padded), union with D
#define WRAW_OFF DBUF_OFF           // 16*800 = 12800 B <= D region

typedef __bf16 bf16x8 __attribute__((ext_vector_type(8)));
typedef float  f32x4  __attribute__((ext_vector_type(4)));

__device__ __forceinline__ unsigned pack2bf(float a, float b) {
    unsigned ua = __float_as_uint(a) + 0x8000u;
    unsigned ub = __float_as_uint(b) + 0x8000u;
    return (ua >> 16) | (ub & 0xFFFF0000u);
}

// barrier waiting only on LDS ops -- global stores stay in flight (r9+)
__device__ __forceinline__ void barrier_lds_only() {
    asm volatile("s_waitcnt lgkmcnt(0)" ::: "memory");
    __builtin_amdgcn_s_barrier();
}

__global__ __launch_bounds__(256, 3)
void conv_mfma_kernel(const float* __restrict__ in,
                      const float* __restrict__ wgt,
                      float* __restrict__ out) {
    __shared__ __align__(16) char lds[LDS_BYTES];

    const int tid  = threadIdx.x;
    const int lane = tid & 63;
    const int w    = tid >> 6;     // wave 0..3
    const int c    = lane & 15;
    const int q    = lane >> 4;
    const int g    = q >> 1;
    const int h    = q & 1;
    const int par  = w >> 1;       // 0: even-x subtiles (shifted v); 1: odd-x

    // ---- XCD swizzle: consecutive same-XCD slots = consecutive y-tiles ----
    const int id  = blockIdx.x;            // 0..4095
    const int xcd = id & 7;
    const int wk  = xcd * 512 + (id >> 3); // bijective
    const int yt  = wk & 127;              // 0..127
    const int p   = wk >> 7;               // 0..31
    const int jg  = p & 1;
    const int bi  = p >> 1;
    const int y0  = yt * RROWS;

    // ---- zero raw-weight region ----
    {
        const uint4 z = make_uint4(0u, 0u, 0u, 0u);
        for (int idx = tid; idx < 800; idx += 256)
            *(uint4*)(lds + WRAW_OFF + idx * 16) = z;
    }
    __syncthreads();

    // ---- fill raw weights: [16 j][10 u][20 v'], v' = v+1 ----
    float* rawF = (float*)(lds + WRAW_OFF);
    const float* wB = wgt + (size_t)(bi * JJ + jg * 16) * (KK * KK);
    for (int idx = tid; idx < 16 * 81; idx += 256) {
        const int j   = idx / 81;
        const int rem = idx - j * 81;
        const int u   = rem / 9;
        const int v   = rem - u * 9;
        rawF[j * 200 + u * 20 + v + 1] = wB[idx];
    }
    __syncthreads();

    // ---- A fragments to registers: afrag[s], j = c, v = 8h + e - 1 + par ----
    bf16x8 afrag[5];
    #pragma unroll
    for (int s = 0; s < 5; ++s) {
        const int u = 2 * s + g;            // 0..9 (u=9 row stays zero)
        const int base = c * 200 + u * 20 + 8 * h + par;  // v'=v+1 folded in
        float wv[8];
        #pragma unroll
        for (int e = 0; e < 8; ++e) wv[e] = rawF[base + e];
        const uint4 pk = make_uint4(pack2bf(wv[0], wv[1]), pack2bf(wv[2], wv[3]),
                                    pack2bf(wv[4], wv[5]), pack2bf(wv[6], wv[7]));
        afrag[s] = __builtin_bit_cast(bf16x8, pk);
    }

    // ---- stage 12 full-width input rows as bf16 (elements -4..523) ----
    const float* inB = in + (size_t)bi * (HH * WW);
    #pragma unroll 1
    for (int idx = tid; idx < NRAW * 66; idx += 256) {
        const int rr = idx / 66;
        const int m  = idx - rr * 66;       // chunk: elements 8m-4 .. 8m+3
        const int gr = y0 - PAD + rr;
        float el[8];
        if ((unsigned)gr < (unsigned)HH) {
            const float* rp = inB + gr * WW + 8 * m - 4;
            if (m >= 1 && m <= 63) {        // interior: 16B-aligned float4 x2
                const float4 a = *(const float4*)rp;
                const float4 b = *(const float4*)(rp + 4);
                el[0]=a.x; el[1]=a.y; el[2]=a.z; el[3]=a.w;
                el[4]=b.x; el[5]=b.y; el[6]=b.z; el[7]=b.w;
            } else {
                #pragma unroll
                for (int t = 0; t < 8; ++t) {
                    const int gx = 8 * m - 4 + t;
                    el[t] = ((unsigned)gx < (unsigned)WW) ? rp[t] : 0.f;
                }
            }
        } else {
            #pragma unroll
            for (int t = 0; t < 8; ++t) el[t] = 0.f;
        }
        *(uint4*)(lds + rr * IN_PITCH_B + m * 16) =
            make_uint4(pack2bf(el[0], el[1]), pack2bf(el[2], el[3]),
                       pack2bf(el[4], el[5]), pack2bf(el[6], el[7]));
    }
    __syncthreads();   // weights read + input staged; D/WRAW region now free

    // ---- main loop: 4 output rows ----
    // subtile i of wave w covers pixels x = 32*(i + 8*(w&1)) + 2c + par
    // B-frag start element e0 = x - 4 + par + 8h (even); dword = (e0+4)/2
    const uint* L = (const uint*)lds;
    const int dwl = c + par + 4 * h + 128 * (w & 1);
    float* D = (float*)(lds + DBUF_OFF);
    const int xb = 256 * (w & 1) + 2 * c + par;
    const size_t plane = (size_t)OH * OW;
    float* outB = out + (size_t)(bi * JJ + jg * 16) * plane;

    #pragma unroll 1
    for (int r = 0; r < RROWS; ++r) {
        f32x4 acc[8];
        #pragma unroll
        for (int i = 0; i < 8; ++i) acc[i] = (f32x4){0.f, 0.f, 0.f, 0.f};

        #pragma unroll
        for (int s = 0; s < 5; ++s) {
            int u = 2 * s + g;
            if (u > 8) u = 0;               // afrag[s]==0 there; finite B ok
            const int rowdw = (r + u) * IN_DW + dwl;
            #pragma unroll
            for (int i = 0; i < 8; ++i) {
                const int d = rowdw + 16 * i;
                const uint4 bf = make_uint4(L[d], L[d + 1], L[d + 2], L[d + 3]);
                acc[i] = __builtin_amdgcn_mfma_f32_16x16x32_bf16(
                             afrag[s], __builtin_bit_cast(bf16x8, bf), acc[i], 0, 0, 0);
            }
        }

        // D-buffer: row m = q*4+rg (j), col = pixel x
        #pragma unroll
        for (int i = 0; i < 8; ++i) {
            const int x = xb + 32 * i;
            #pragma unroll
            for (int rg = 0; rg < 4; ++rg)
                D[(q * 4 + rg) * D_PITCH + x] = acc[i][rg];
        }
        barrier_lds_only();

        // store: 4 j per wave, 4 x-segments, float2/lane -> 2040B/row runs
        const int y = y0 + r;
        if (y < OH) {
            #pragma unroll
            for (int jj = 0; jj < 4; ++jj) {
                const int jl = w * 4 + jj;
                float* op = outB + (size_t)jl * plane + (size_t)y * OW;
                #pragma unroll
                for (int seg = 0; seg < 4; ++seg) {
                    const int px = seg * 128 + 2 * lane;
                    if (px + 1 < OW)
                        *(float2*)(op + px) = *(const float2*)&D[jl * D_PITCH + px];
                }
            }
        }
        barrier_lds_only();
    }
}

extern "C" void kernel_launch(void* const* d_in, const int* in_sizes, int n_in,
                              void* d_out, int out_size, void* d_ws, size_t ws_size,
                              hipStream_t stream) {
    const float* inp = (const float*)d_in[0];   // [16,1,512,512] f32
    const float* wgt = (const float*)d_in[1];   // [16,32,9,9]    f32
    float* out = (float*)d_out;                 // [16,32,510,510] f32

    conv_mfma_kernel<<<dim3(4096), 256, 0, stream>>>(inp, wgt, out);
}